// Round 1
// baseline (100.681 us; speedup 1.0000x reference)
//
#include <hip/hip_runtime.h>

// FitStepOutput: per-row exclusive-prefix cumsum of (1-2*x), argmin (first-min
// tie-break), then midpoint of surrounding bin edges.
//
// Design: ONE THREAD PER ROW with a strictly sequential fp32 accumulation in
// the exact order of np.cumsum — this makes the argmin decision bit-exact vs
// the NumPy reference (tree scans change rounding and flip near-tie argmins,
// which jump a whole bin gap >> threshold). Memory-bound: 512 MB read.

#define NBINS 128

__global__ __launch_bounds__(256) void fitstep_kernel(
    const float* __restrict__ inp,
    const float* __restrict__ bins,
    float* __restrict__ out,
    int nrows)
{
    int row = blockIdx.x * blockDim.x + threadIdx.x;
    if (row >= nrows) return;

    const float4* r4 = reinterpret_cast<const float4*>(inp + (size_t)row * NBINS);

    // scores[0] = 0 is a candidate (index 0).
    float score   = 0.0f;
    float best    = 0.0f;
    int   bestIdx = 0;

    #pragma unroll 8
    for (int j = 0; j < NBINS / 4; ++j) {
        float4 v = r4[j];
        float xs0 = v.x, xs1 = v.y, xs2 = v.z, xs3 = v.w;

        // Sequential, same rounding order as np: delta = 1 - 2*x (2*x exact,
        // one rounding), then score += delta (one rounding). Strict < keeps
        // the FIRST minimum, matching np.argmin.
        score += (1.0f - 2.0f * xs0);
        if (score < best) { best = score; bestIdx = j * 4 + 1; }
        score += (1.0f - 2.0f * xs1);
        if (score < best) { best = score; bestIdx = j * 4 + 2; }
        score += (1.0f - 2.0f * xs2);
        if (score < best) { best = score; bestIdx = j * 4 + 3; }
        score += (1.0f - 2.0f * xs3);
        if (score < best) { best = score; bestIdx = j * 4 + 4; }
    }

    // bins_to_select = [bins[0], bins[0..127], bins[127]]  (len 130)
    // chosen = (b2s[idx] + b2s[idx+1]) * 0.5
    //   b2s[idx]   = bins[max(idx-1, 0)]      (idx in [0,128])
    //   b2s[idx+1] = bins[min(idx, 127)]
    int lo = bestIdx - 1; if (lo < 0) lo = 0;
    int hi = bestIdx;     if (hi > NBINS - 1) hi = NBINS - 1;
    out[row] = (bins[lo] + bins[hi]) * 0.5f;
}

extern "C" void kernel_launch(void* const* d_in, const int* in_sizes, int n_in,
                              void* d_out, int out_size, void* d_ws, size_t ws_size,
                              hipStream_t stream)
{
    const float* inp  = (const float*)d_in[0];
    const float* bins = (const float*)d_in[1];
    float* out = (float*)d_out;

    int nrows = in_sizes[0] / NBINS;  // B = 1048576
    int block = 256;
    int grid  = (nrows + block - 1) / block;

    fitstep_kernel<<<grid, block, 0, stream>>>(inp, bins, out, nrows);
}

// Round 2
// 94.570 us; speedup vs baseline: 1.0646x; 1.0646x over previous
//
#include <hip/hip_runtime.h>

// FitStepOutput: per-row exclusive-prefix cumsum of (1-2*x), argmin (first-min
// tie-break), midpoint of surrounding bin edges.
//
// R2: coalesced cooperative loads -> XOR-swizzled LDS (double-buffered),
// thread-per-row sequential scan from LDS (bit-exact vs np.cumsum order).
// T14 pipeline: chunk c+1 global loads issued before scan of chunk c.

#define NBINS 128
#define ROWS  256          // rows per block == threads per block
#define CHUNK 32           // columns per chunk
#define NCHUNK (NBINS / CHUNK)

__global__ __launch_bounds__(ROWS) void fitstep_kernel(
    const float* __restrict__ inp,
    const float* __restrict__ bins,
    float* __restrict__ out,
    int nrows)
{
    __shared__ float lds[2][ROWS * CHUNK];   // 2 x 32 KB = 64 KB

    const int t = threadIdx.x;
    const size_t rowbase = (size_t)blockIdx.x * ROWS;

    if (rowbase + ROWS <= (size_t)nrows) {
        const float* base = inp + rowbase * NBINS;
        float4 pf[8];

        // prologue: load + stage chunk 0
        // mapping: flat f = i*256 + t -> row r = f/8, float4-slot k = f%8
        // global: 8-lane groups read contiguous 128B (full L2 lines)
        #pragma unroll
        for (int i = 0; i < 8; ++i) {
            int f = i * ROWS + t;
            int r = f >> 3, k = f & 7;
            pf[i] = *reinterpret_cast<const float4*>(base + (size_t)r * NBINS + k * 4);
        }
        #pragma unroll
        for (int i = 0; i < 8; ++i) {
            int f = i * ROWS + t;
            int r = f >> 3, k = f & 7;
            int slot = k ^ (r & 7);            // XOR swizzle: conflict-free b128
            *reinterpret_cast<float4*>(&lds[0][r * CHUNK + slot * 4]) = pf[i];
        }
        __syncthreads();

        float score = 0.0f, best = 0.0f;
        int bestIdx = 0;

        for (int c = 0; c < NCHUNK; ++c) {
            const int buf = c & 1;

            // T14: issue next chunk's global loads BEFORE scanning this one
            if (c + 1 < NCHUNK) {
                #pragma unroll
                for (int i = 0; i < 8; ++i) {
                    int f = i * ROWS + t;
                    int r = f >> 3, k = f & 7;
                    pf[i] = *reinterpret_cast<const float4*>(
                        base + (size_t)r * NBINS + (c + 1) * CHUNK + k * 4);
                }
            }

            // scan 32 columns from LDS, exact np.cumsum order, strict < for
            // first-occurrence argmin
            #pragma unroll
            for (int j = 0; j < 8; ++j) {
                int slot = j ^ (t & 7);
                float4 v = *reinterpret_cast<const float4*>(
                    &lds[buf][t * CHUNK + slot * 4]);
                int colbase = c * CHUNK + j * 4;
                score += (1.0f - 2.0f * v.x);
                if (score < best) { best = score; bestIdx = colbase + 1; }
                score += (1.0f - 2.0f * v.y);
                if (score < best) { best = score; bestIdx = colbase + 2; }
                score += (1.0f - 2.0f * v.z);
                if (score < best) { best = score; bestIdx = colbase + 3; }
                score += (1.0f - 2.0f * v.w);
                if (score < best) { best = score; bestIdx = colbase + 4; }
            }

            // write next chunk into the other buffer, then barrier
            if (c + 1 < NCHUNK) {
                #pragma unroll
                for (int i = 0; i < 8; ++i) {
                    int f = i * ROWS + t;
                    int r = f >> 3, k = f & 7;
                    int slot = k ^ (r & 7);
                    *reinterpret_cast<float4*>(
                        &lds[buf ^ 1][r * CHUNK + slot * 4]) = pf[i];
                }
                __syncthreads();
            }
        }

        int lo = bestIdx - 1; if (lo < 0) lo = 0;
        int hi = bestIdx;     if (hi > NBINS - 1) hi = NBINS - 1;
        out[rowbase + t] = (bins[lo] + bins[hi]) * 0.5f;
    } else {
        // tail fallback (not hit for B = 1M = 4096 * 256): per-thread path
        size_t row = rowbase + t;
        if (row >= (size_t)nrows) return;
        const float* rp = inp + row * NBINS;
        float score = 0.0f, best = 0.0f;
        int bestIdx = 0;
        for (int j = 0; j < NBINS; ++j) {
            score += (1.0f - 2.0f * rp[j]);
            if (score < best) { best = score; bestIdx = j + 1; }
        }
        int lo = bestIdx - 1; if (lo < 0) lo = 0;
        int hi = bestIdx;     if (hi > NBINS - 1) hi = NBINS - 1;
        out[row] = (bins[lo] + bins[hi]) * 0.5f;
    }
}

extern "C" void kernel_launch(void* const* d_in, const int* in_sizes, int n_in,
                              void* d_out, int out_size, void* d_ws, size_t ws_size,
                              hipStream_t stream)
{
    const float* inp  = (const float*)d_in[0];
    const float* bins = (const float*)d_in[1];
    float* out = (float*)d_out;

    int nrows = in_sizes[0] / NBINS;   // B = 1048576
    int grid  = (nrows + ROWS - 1) / ROWS;

    fitstep_kernel<<<grid, ROWS, 0, stream>>>(inp, bins, out, nrows);
}